// Round 2
// baseline (2004.728 us; speedup 1.0000x reference)
//
#include <hip/hip_runtime.h>
#include <cstdint>

// Problem constants (from reference: B=32, C=1, H=W=512, 200 iters, top-100)
#define IW 512
#define IH 512
#define HW 262144          // 512*512
#define NIMG 32
#define NSEG 262145        // HW+1 segments per image
#define MAXD 100
// Propagation tiling: 64x64 register tile, 8-iter halo, 48x48 core, 25 passes
#define TILE 64
#define CORE 48
#define HALO 8
#define NPASS 25
#define NT 11              // ceil(512/48)

// ---------------- workspace layout (bytes) ----------------
// labA  @ 0          (33,554,432) -- aliased by counts after last prop pass
// labB  @ 33554688   (33,554,432)
// hist  @ 67109120   (32*8192*4 = 1,048,576)
// small @ 68157696   (pref/need/len/sel/rank arrays/bbox arrays)
#define OFF_LABB  33554688ull
#define OFF_HIST  67109120ull
#define OFF_SMALL 68157696ull

__device__ __forceinline__ int imax3(int a, int b, int c) {
    int m = a > b ? a : b;
    return m > c ? m : c;
}

// ---------------- 1. init labels: lab = fg ? (pixelIdx+1) : 0 ----------------
__global__ __launch_bounds__(256) void init_labels(const float* __restrict__ img,
                                                   int* __restrict__ lab) {
    size_t stride = (size_t)gridDim.x * blockDim.x;
    for (size_t i = (size_t)blockIdx.x * blockDim.x + threadIdx.x;
         i < (size_t)NIMG * HW; i += stride) {
        int p = (int)(i & (HW - 1));             // pixel index within image
        // x/255 > 0.5  <=>  x > 127.5 (input values are exact integers 0..255)
        lab[i] = (img[i] > 127.5f) ? (p + 1) : 0;
    }
}

// ---------------- 2. propagation: 8 masked maxpool iterations per pass -------
// 1 wave per 64x64 tile. Lane owns column strip v[64] in registers.
// Horizontal 3-max via shfl +-1 (tile-edge garbage absorbed by 8-wide halo,
// and 0 is the CORRECT out-of-image value at image borders since loads give 0).
// mask == (v != 0): fg labels are monotone >=1, bg stays 0.
__global__ __launch_bounds__(64) void prop_pass(const int* __restrict__ in,
                                                int* __restrict__ out) {
    const int img = blockIdx.z;
    const int tx0 = blockIdx.x * CORE - HALO;
    const int ty0 = blockIdx.y * CORE - HALO;
    const int lane = threadIdx.x;
    const int gx = tx0 + lane;
    const int* ip = in + (size_t)img * HW;
    int* op = out + (size_t)img * HW;
    const bool colok = (gx >= 0) && (gx < IW);

    int v[TILE];
#pragma unroll
    for (int i = 0; i < TILE; ++i) {
        int gy = ty0 + i;
        v[i] = (colok && gy >= 0 && gy < IH) ? ip[gy * IW + gx] : 0;
    }

#pragma unroll 1
    for (int it = 0; it < HALO; ++it) {
        int hprev = 0;
        int l0 = __shfl_up(v[0], 1, 64);
        int r0 = __shfl_down(v[0], 1, 64);
        int hcur = imax3(l0, v[0], r0);
#pragma unroll
        for (int i = 0; i < TILE; ++i) {
            int hnext = 0;
            if (i < TILE - 1) {
                int l = __shfl_up(v[i + 1], 1, 64);
                int r = __shfl_down(v[i + 1], 1, 64);
                hnext = imax3(l, v[i + 1], r);
            }
            int nv = imax3(hprev, hcur, hnext);
            v[i] = (v[i] == 0) ? 0 : nv;   // apply mask (bg stays 0)
            hprev = hcur; hcur = hnext;
        }
    }

    // write 48x48 core
    if (lane >= HALO && lane < TILE - HALO && gx < IW) {
#pragma unroll
        for (int i = HALO; i < TILE - HALO; ++i) {
            int gy = ty0 + i;
            if (gy < IH) op[gy * IW + gx] = v[i];
        }
    }
}

// ---------------- 3. per-label pixel counts (LDS hash aggregation) -----------
#define HASHN 2048
__global__ __launch_bounds__(256) void count_pass(const int* __restrict__ lab,
                                                  unsigned* __restrict__ counts) {
    __shared__ unsigned hkey[HASHN];
    __shared__ unsigned hval[HASHN];
    const int img = blockIdx.y;
    const int rb = blockIdx.x * 16;       // 16 rows per block
    for (int t = threadIdx.x; t < HASHN; t += 256) { hkey[t] = 0; hval[t] = 0; }
    __syncthreads();
    const int* lp = lab + (size_t)img * HW + rb * IW;
    unsigned* cbase = counts + (size_t)img * NSEG;
    for (int p = threadIdx.x; p < 16 * IW; p += 256) {
        int l = lp[p];
        if (l == 0) continue;
        unsigned ul = (unsigned)l;
        unsigned h = (ul * 2654435761u) >> 21;   // 11-bit hash
        bool done = false;
        for (int probe = 0; probe < 64; ++probe) {
            unsigned idx = (h + probe) & (HASHN - 1);
            unsigned k = hkey[idx];
            if (k == ul) { atomicAdd(&hval[idx], 1u); done = true; break; }
            if (k == 0u) {
                unsigned old = atomicCAS(&hkey[idx], 0u, ul);
                if (old == 0u || old == ul) { atomicAdd(&hval[idx], 1u); done = true; break; }
            }
        }
        if (!done) atomicAdd(&cbase[ul], 1u);    // rare fallback
    }
    __syncthreads();
    for (int t = threadIdx.x; t < HASHN; t += 256)
        if (hkey[t]) atomicAdd(&cbase[hkey[t]], hval[t]);
}

// ---------------- 4. exact top-100 via 3-round radix select on 38-bit key ----
// key = (count<<19) | (HW - i): unique per image; order == (count desc, i asc)
// == lax.top_k tie semantics.
__global__ void init_need(unsigned* need) {
    if (threadIdx.x < NIMG) need[threadIdx.x] = 100u;
}

__global__ __launch_bounds__(256) void sel_hist(const unsigned* __restrict__ counts,
                                                const unsigned long long* __restrict__ pref,
                                                unsigned* __restrict__ hist,
                                                int shift, int bits, int isRound0) {
    __shared__ unsigned lh[8192];
    const int img = blockIdx.y;
    const int bins = 1 << bits;
    for (int t = threadIdx.x; t < bins; t += 256) lh[t] = 0;
    __syncthreads();
    const unsigned* cb = counts + (size_t)img * NSEG;
    unsigned long long pf = pref[img];
    unsigned zloc = 0;
    for (int i = blockIdx.x * 256 + threadIdx.x; i < NSEG; i += gridDim.x * 256) {
        unsigned c = cb[i];
        unsigned long long key = ((unsigned long long)c << 19) | (unsigned)(HW - i);
        if (isRound0) {
            if (c == 0) { zloc++; continue; }       // zeros all land in bin 0
            atomicAdd(&lh[(unsigned)(key >> shift) & (bins - 1)], 1u);
        } else {
            if ((key >> (shift + bits)) == pf)
                atomicAdd(&lh[(unsigned)(key >> shift) & (bins - 1)], 1u);
        }
    }
    if (isRound0 && zloc) atomicAdd(&lh[0], zloc);
    __syncthreads();
    unsigned* gh = hist + (size_t)img * 8192;
    for (int t = threadIdx.x; t < bins; t += 256) {
        unsigned x = lh[t];
        if (x) atomicAdd(&gh[t], x);
    }
}

__global__ __launch_bounds__(256) void sel_scan(const unsigned* __restrict__ hist,
                                                unsigned long long* __restrict__ pref,
                                                unsigned* __restrict__ need, int bits) {
    __shared__ unsigned csum[256];
    const int img = blockIdx.x;
    const int bins = 1 << bits;
    const int C = bins / 256;
    const unsigned* gh = hist + (size_t)img * 8192;
    unsigned s = 0;
    for (int j = 0; j < C; ++j) s += gh[threadIdx.x * C + j];
    csum[threadIdx.x] = s;
    __syncthreads();
    if (threadIdx.x == 0) {                 // suffix-sum of 256 chunk sums
        unsigned acc = 0;
        for (int t = 255; t >= 0; --t) { unsigned x = csum[t]; csum[t] = acc; acc += x; }
    }
    __syncthreads();
    unsigned nd = need[img];
    __syncthreads();                        // all read nd before winner writes
    unsigned cum = csum[threadIdx.x];       // #keys above this chunk
    for (int j = C - 1; j >= 0; --j) {
        unsigned hv = gh[threadIdx.x * C + j];
        if (hv && cum < nd && nd <= cum + hv) {   // unique crossing bin
            pref[img] = (pref[img] << bits) | (unsigned)(threadIdx.x * C + j);
            need[img] = nd - cum;
        }
        cum += hv;
    }
}

__global__ __launch_bounds__(256) void collect_sel(const unsigned* __restrict__ counts,
                                                   const unsigned long long* __restrict__ pref,
                                                   unsigned* __restrict__ len,
                                                   unsigned long long* __restrict__ sel) {
    const int img = blockIdx.y;
    const unsigned* cb = counts + (size_t)img * NSEG;
    unsigned long long k100 = pref[img];     // exact 100th-largest key
    for (int i = blockIdx.x * 256 + threadIdx.x; i < NSEG; i += gridDim.x * 256) {
        unsigned c = cb[i];
        unsigned long long key = ((unsigned long long)c << 19) | (unsigned)(HW - i);
        if (key >= k100) {
            unsigned pos = atomicAdd(&len[img], 1u);
            if (pos < MAXD) sel[(size_t)img * MAXD + pos] = key;
        }
    }
}

// rank-sort the 100 keys (desc) and also produce a label-ascending view for
// binary search in the bbox pass.
__global__ __launch_bounds__(128) void sort_sel(const unsigned long long* __restrict__ sel,
                                                unsigned* __restrict__ rank_count,
                                                unsigned* __restrict__ lab_asc,
                                                unsigned* __restrict__ rank_of_lab) {
    __shared__ unsigned long long k[MAXD];
    __shared__ unsigned labr[MAXD];
    const int img = blockIdx.x;
    int t = threadIdx.x;
    if (t < MAXD) k[t] = sel[(size_t)img * MAXD + t];
    __syncthreads();
    if (t < MAXD) {
        unsigned long long key = k[t];
        int r = 0;
        for (int j = 0; j < MAXD; ++j) r += (k[j] > key);   // keys unique
        rank_count[img * MAXD + r] = (unsigned)(key >> 19);
        labr[r] = HW - (unsigned)(key & 0x7FFFFu);
    }
    __syncthreads();
    if (t < MAXD) {
        unsigned lab = labr[t];                  // t is the rank here
        int lr = 0;
        for (int j = 0; j < MAXD; ++j) lr += (labr[j] < lab);
        lab_asc[img * MAXD + lr] = lab;
        rank_of_lab[img * MAXD + lr] = (unsigned)t;
    }
}

// ---------------- 5. bbox of selected labels (LDS pre-reduction) -------------
__global__ __launch_bounds__(256) void bbox_pass(const int* __restrict__ lab,
                                                 const unsigned* __restrict__ lab_asc,
                                                 const unsigned* __restrict__ rank_of_lab,
                                                 unsigned* __restrict__ bxmin,
                                                 unsigned* __restrict__ bymin,
                                                 unsigned* __restrict__ bxmax,
                                                 unsigned* __restrict__ bymax) {
    __shared__ unsigned sl[MAXD], sr[MAXD];
    __shared__ unsigned sxmin[MAXD], symin[MAXD], sxmax[MAXD], symax[MAXD];
    const int img = blockIdx.y;
    const int rb = blockIdx.x * 16;
    int t = threadIdx.x;
    if (t < MAXD) {
        sl[t] = lab_asc[img * MAXD + t];
        sr[t] = rank_of_lab[img * MAXD + t];
        sxmin[t] = 0xFFFFFFFFu; symin[t] = 0xFFFFFFFFu; sxmax[t] = 0u; symax[t] = 0u;
    }
    __syncthreads();
    const int* lp = lab + (size_t)img * HW + rb * IW;
    for (int p = t; p < 16 * IW; p += 256) {
        int l = lp[p];
        if (!l) continue;
        unsigned ul = (unsigned)l;
        int lo = 0, hi = MAXD - 1, f = -1;        // binary search (labels unique)
        while (lo <= hi) {
            int mid = (lo + hi) >> 1;
            unsigned sv = sl[mid];
            if (sv == ul) { f = mid; break; }
            if (sv < ul) lo = mid + 1; else hi = mid - 1;
        }
        if (f >= 0) {
            unsigned r = sr[f];
            unsigned x = (unsigned)(p & (IW - 1));
            unsigned y = (unsigned)(rb + (p >> 9));
            atomicMin(&sxmin[r], x); atomicMax(&sxmax[r], x);
            atomicMin(&symin[r], y); atomicMax(&symax[r], y);
        }
    }
    __syncthreads();
    if (t < MAXD && sxmin[t] != 0xFFFFFFFFu) {
        atomicMin(&bxmin[img * MAXD + t], sxmin[t]);
        atomicMax(&bxmax[img * MAXD + t], sxmax[t]);
        atomicMin(&bymin[img * MAXD + t], symin[t]);
        atomicMax(&bymax[img * MAXD + t], symax[t]);
    }
}

// ---------------- 6. finalize: [xmin,ymin,xmax,ymax] or zeros ----------------
__global__ __launch_bounds__(256) void final_out(const unsigned* __restrict__ rank_count,
                                                 const unsigned* __restrict__ bxmin,
                                                 const unsigned* __restrict__ bymin,
                                                 const unsigned* __restrict__ bxmax,
                                                 const unsigned* __restrict__ bymax,
                                                 float* __restrict__ out) {
    int id = blockIdx.x * 256 + threadIdx.x;
    if (id >= NIMG * MAXD) return;
    unsigned c = rank_count[id];
    float4 b = make_float4(0.f, 0.f, 0.f, 0.f);
    if (c) b = make_float4((float)bxmin[id], (float)bymin[id],
                           (float)bxmax[id], (float)bymax[id]);
    reinterpret_cast<float4*>(out)[id] = b;
}

// ---------------- launch ----------------
extern "C" void kernel_launch(void* const* d_in, const int* in_sizes, int n_in,
                              void* d_out, int out_size, void* d_ws, size_t ws_size,
                              hipStream_t stream) {
    (void)in_sizes; (void)n_in; (void)out_size; (void)ws_size;
    const float* img = (const float*)d_in[0];
    char* ws = (char*)d_ws;

    int* labA = (int*)ws;
    int* labB = (int*)(ws + OFF_LABB);
    unsigned* counts = (unsigned*)labA;                 // alias: labA dead after last pass
    unsigned* hist = (unsigned*)(ws + OFF_HIST);
    char* sm = ws + OFF_SMALL;
    unsigned long long* pref = (unsigned long long*)sm;             // 256 B
    unsigned* need = (unsigned*)(sm + 256);                         // 128 B
    unsigned* len  = (unsigned*)(sm + 512);                         // 128 B
    unsigned long long* sel = (unsigned long long*)(sm + 1024);     // 25600 B
    unsigned* rank_count  = (unsigned*)(sm + 1024 + 25600);
    unsigned* lab_asc     = rank_count + NIMG * MAXD;
    unsigned* rank_of_lab = lab_asc + NIMG * MAXD;
    unsigned* bxmin = rank_of_lab + NIMG * MAXD;
    unsigned* bymin = bxmin + NIMG * MAXD;
    unsigned* bxmax = bymin + NIMG * MAXD;
    unsigned* bymax = bxmax + NIMG * MAXD;
    float* out = (float*)d_out;

    init_labels<<<2048, 256, 0, stream>>>(img, labA);

    // 25 passes x 8 iterations = exactly 200 masked maxpool iterations
    dim3 pg(NT, NT, NIMG);
    const int* pin = labA; int* pout = labB;
    for (int p = 0; p < NPASS; ++p) {
        prop_pass<<<pg, 64, 0, stream>>>(pin, pout);
        int* tmp = (int*)pin; pin = pout; pout = tmp;
    }
    const int* flab = pin;   // NPASS odd -> labB

    // init small buffers + counts (labA safe to overwrite now; stream-ordered)
    hipMemsetAsync(counts, 0, (size_t)NIMG * NSEG * 4, stream);
    hipMemsetAsync(pref, 0, 256, stream);
    hipMemsetAsync(len, 0, 128, stream);
    hipMemsetAsync(bxmin, 0xFF, NIMG * MAXD * 4, stream);
    hipMemsetAsync(bymin, 0xFF, NIMG * MAXD * 4, stream);
    hipMemsetAsync(bxmax, 0, NIMG * MAXD * 4, stream);
    hipMemsetAsync(bymax, 0, NIMG * MAXD * 4, stream);
    init_need<<<1, 64, 0, stream>>>(need);

    count_pass<<<dim3(32, NIMG), 256, 0, stream>>>(flab, counts);

    const int shifts[3] = {25, 12, 0};
    const int bitsr[3] = {13, 13, 12};
    for (int r = 0; r < 3; ++r) {
        hipMemsetAsync(hist, 0, (size_t)NIMG * 8192 * 4, stream);
        sel_hist<<<dim3(4, NIMG), 256, 0, stream>>>(counts, pref, hist,
                                                    shifts[r], bitsr[r], r == 0 ? 1 : 0);
        sel_scan<<<NIMG, 256, 0, stream>>>(hist, pref, need, bitsr[r]);
    }
    collect_sel<<<dim3(4, NIMG), 256, 0, stream>>>(counts, pref, len, sel);
    sort_sel<<<NIMG, 128, 0, stream>>>(sel, rank_count, lab_asc, rank_of_lab);

    bbox_pass<<<dim3(32, NIMG), 256, 0, stream>>>(flab, lab_asc, rank_of_lab,
                                                  bxmin, bymin, bxmax, bymax);
    final_out<<<(NIMG * MAXD + 255) / 256, 256, 0, stream>>>(rank_count, bxmin, bymin,
                                                             bxmax, bymax, out);
}